// Round 1
// baseline (3625.943 us; speedup 1.0000x reference)
//
#include <hip/hip_runtime.h>

// Steerable pyramid, depthwise convs, NHWC fp32, C=16 (= 4 x float4).
// All convs are per-channel 2D cross-correlation with one shared 2D filter.

static __device__ __forceinline__ float4 fmaf4(float f, float4 v, float4 a) {
    a.x = fmaf(f, v.x, a.x);
    a.y = fmaf(f, v.y, a.y);
    a.z = fmaf(f, v.z, a.z);
    a.w = fmaf(f, v.w, a.w);
    return a;
}

// 9x9, stride 1, pad 4, TWO filters (hi0 + lo0) fused over one input read.
__global__ __launch_bounds__(256) void conv9_dual(
    const float4* __restrict__ in,
    float4* __restrict__ o0, float4* __restrict__ o1,
    const float* __restrict__ f0, const float* __restrict__ f1,
    int N, int H, int W)
{
    int tid = blockIdx.x * 256 + threadIdx.x;
    int total = N * H * W * 4;
    if (tid >= total) return;
    int c4 = tid & 3;
    int x  = (tid >> 2) % W;
    int yz = (tid >> 2) / W;
    int y  = yz % H;
    int n  = yz / H;
    const float4* base = in + (size_t)n * H * W * 4;
    int selfIdx = (y * W + x) * 4 + c4;   // always in-range fallback

    float4 a0 = make_float4(0.f, 0.f, 0.f, 0.f);
    float4 a1 = a0;
    #pragma unroll
    for (int dy = 0; dy < 9; ++dy) {
        int iy = y + dy - 4;
        bool oky = (unsigned)iy < (unsigned)H;
        #pragma unroll
        for (int dx = 0; dx < 9; ++dx) {
            int ix = x + dx - 4;
            bool ok = oky && ((unsigned)ix < (unsigned)W);
            int idx = ok ? ((iy * W + ix) * 4 + c4) : selfIdx;
            float w0 = ok ? f0[dy * 9 + dx] : 0.f;
            float w1 = ok ? f1[dy * 9 + dx] : 0.f;
            float4 v = base[idx];
            a0 = fmaf4(w0, v, a0);
            a1 = fmaf4(w1, v, a1);
        }
    }
    o0[tid] = a0;
    o1[tid] = a1;
}

// 9x9, stride 1, pad 4, FOUR contiguous filters (bfilts) fused.
__global__ __launch_bounds__(256) void conv9_quad(
    const float4* __restrict__ in,
    float4* __restrict__ o0, float4* __restrict__ o1,
    float4* __restrict__ o2, float4* __restrict__ o3,
    const float* __restrict__ filt,   // 4*81 contiguous
    int N, int H, int W)
{
    int tid = blockIdx.x * 256 + threadIdx.x;
    int total = N * H * W * 4;
    if (tid >= total) return;
    int c4 = tid & 3;
    int x  = (tid >> 2) % W;
    int yz = (tid >> 2) / W;
    int y  = yz % H;
    int n  = yz / H;
    const float4* base = in + (size_t)n * H * W * 4;
    int selfIdx = (y * W + x) * 4 + c4;

    float4 a0 = make_float4(0.f, 0.f, 0.f, 0.f);
    float4 a1 = a0, a2 = a0, a3 = a0;
    #pragma unroll
    for (int dy = 0; dy < 9; ++dy) {
        int iy = y + dy - 4;
        bool oky = (unsigned)iy < (unsigned)H;
        #pragma unroll
        for (int dx = 0; dx < 9; ++dx) {
            int ix = x + dx - 4;
            bool ok = oky && ((unsigned)ix < (unsigned)W);
            int idx = ok ? ((iy * W + ix) * 4 + c4) : selfIdx;
            int t = dy * 9 + dx;
            float w0 = ok ? filt[t]       : 0.f;
            float w1 = ok ? filt[81 + t]  : 0.f;
            float w2 = ok ? filt[162 + t] : 0.f;
            float w3 = ok ? filt[243 + t] : 0.f;
            float4 v = base[idx];
            a0 = fmaf4(w0, v, a0);
            a1 = fmaf4(w1, v, a1);
            a2 = fmaf4(w2, v, a2);
            a3 = fmaf4(w3, v, a3);
        }
    }
    o0[tid] = a0;
    o1[tid] = a1;
    o2[tid] = a2;
    o3[tid] = a3;
}

// 17x17, stride 2, explicit pad 8.  out is (N, H/2, W/2, C).
__global__ __launch_bounds__(256) void conv17_s2(
    const float4* __restrict__ in, float4* __restrict__ outp,
    const float* __restrict__ f, int N, int H, int W)
{
    int Ho = H >> 1, Wo = W >> 1;
    int tid = blockIdx.x * 256 + threadIdx.x;
    int total = N * Ho * Wo * 4;
    if (tid >= total) return;
    int c4 = tid & 3;
    int xo = (tid >> 2) % Wo;
    int yz = (tid >> 2) / Wo;
    int yo = yz % Ho;
    int n  = yz / Ho;
    const float4* base = in + (size_t)n * H * W * 4;
    int selfIdx = ((2 * yo) * W + 2 * xo) * 4 + c4;

    float4 a = make_float4(0.f, 0.f, 0.f, 0.f);
    for (int dy = 0; dy < 17; ++dy) {
        int iy = 2 * yo + dy - 8;
        bool oky = (unsigned)iy < (unsigned)H;
        #pragma unroll
        for (int dx = 0; dx < 17; ++dx) {
            int ix = 2 * xo + dx - 8;
            bool ok = oky && ((unsigned)ix < (unsigned)W);
            int idx = ok ? ((iy * W + ix) * 4 + c4) : selfIdx;
            float w = ok ? f[dy * 17 + dx] : 0.f;
            float4 v = base[idx];
            a = fmaf4(w, v, a);
        }
    }
    outp[tid] = a;
}

extern "C" void kernel_launch(void* const* d_in, const int* in_sizes, int n_in,
                              void* d_out, int out_size, void* d_ws, size_t ws_size,
                              hipStream_t stream) {
    const float* image   = (const float*)d_in[0];
    const float* lo0filt = (const float*)d_in[1];
    const float* hi0filt = (const float*)d_in[2];
    const float* lofilt  = (const float*)d_in[3];
    const float* bfilts  = (const float*)d_in[4];
    float* out = (float*)d_out;
    float* ws  = (float*)d_ws;

    const int N = 8, C = 16;
    const int Hs[5] = {256, 128, 64, 32, 16};
    size_t sz[5];
    for (int s = 0; s < 5; ++s) sz[s] = (size_t)N * Hs[s] * Hs[s] * C;

    // Workspace: lo at scales 0..3 (scale 4 goes straight to d_out).
    float* lo_buf[4];
    size_t woff = 0;
    for (int s = 0; s < 4; ++s) { lo_buf[s] = ws + woff; woff += sz[s]; }

    // Output layout (reversed pyramid, flat-concatenated):
    // [ lo_final | s=3 b=3..0 | s=2 b=3..0 | s=1 b=3..0 | s=0 b=3..0 | hi0 ]
    float* out_lofinal = out;
    size_t o = sz[4];
    float* band_ptr[4][4];
    for (int s = 3; s >= 0; --s)
        for (int b = 3; b >= 0; --b) { band_ptr[s][b] = out + o; o += sz[s]; }
    float* out_hi0 = out + o;

    // hi0 + lo0 from the image (one read, two filters)
    {
        int H = Hs[0];
        int total = N * H * H * 4;
        conv9_dual<<<total / 256, 256, 0, stream>>>(
            (const float4*)image, (float4*)out_hi0, (float4*)lo_buf[0],
            hi0filt, lo0filt, N, H, H);
    }

    for (int s = 0; s < 4; ++s) {
        int H = Hs[s];
        int total = N * H * H * 4;
        // 4 band convs fused (one lo read)
        conv9_quad<<<total / 256, 256, 0, stream>>>(
            (const float4*)lo_buf[s],
            (float4*)band_ptr[s][0], (float4*)band_ptr[s][1],
            (float4*)band_ptr[s][2], (float4*)band_ptr[s][3],
            bfilts, N, H, H);
        // downsample lo
        int totalo = N * (H / 2) * (H / 2) * 4;
        float4* dst = (s < 3) ? (float4*)lo_buf[s + 1] : (float4*)out_lofinal;
        conv17_s2<<<totalo / 256, 256, 0, stream>>>(
            (const float4*)lo_buf[s], dst, lofilt, N, H, H);
    }
}

// Round 2
// 389.882 us; speedup vs baseline: 9.3001x; 9.3001x over previous
//
#include <hip/hip_runtime.h>

// Steerable pyramid, depthwise convs, NHWC fp32, C=16 (= 4 x float4).
// All dims are powers of two; H == W at every scale.

static __device__ __forceinline__ float4 fmaf4(float f, float4 v, float4 a) {
    a.x = fmaf(f, v.x, a.x);
    a.y = fmaf(f, v.y, a.y);
    a.z = fmaf(f, v.z, a.z);
    a.w = fmaf(f, v.w, a.w);
    return a;
}

static __device__ __forceinline__ int clampi(int v, int lo, int hi) {
    return min(max(v, lo), hi);
}

// 9x9, stride 1, pad 4. NF==2: filters f0,f1 (hi0/lo0). NF==4: f0 is 4*81 contiguous.
template <int NF>
__global__ __launch_bounds__(256, 4) void conv9_multi(
    const float4* __restrict__ in,
    float4* __restrict__ out0, float4* __restrict__ out1,
    float4* __restrict__ out2, float4* __restrict__ out3,
    const float* __restrict__ f0, const float* __restrict__ f1,
    int logW)
{
    const int W = 1 << logW;
    int tid = blockIdx.x * 256 + threadIdx.x;
    int c4 = tid & 3;
    int x  = (tid >> 2) & (W - 1);
    int y  = (tid >> (2 + logW)) & (W - 1);
    int n  = tid >> (2 + 2 * logW);
    const float4* base = in + (((size_t)n << (2 * logW)) << 2);

    float4 a0 = make_float4(0.f, 0.f, 0.f, 0.f);
    float4 a1 = a0, a2 = a0, a3 = a0;
    #pragma unroll 1
    for (int dy = 0; dy < 9; ++dy) {
        int iy = y + dy - 4;
        bool oky = (unsigned)iy < (unsigned)W;
        int iyc = clampi(iy, 0, W - 1);
        #pragma unroll
        for (int dx = 0; dx < 9; ++dx) {
            int ix = x + dx - 4;
            bool ok = oky && ((unsigned)ix < (unsigned)W);
            int ixc = clampi(ix, 0, W - 1);
            float4 v = base[(((iyc << logW) + ixc) << 2) + c4];
            v.x = ok ? v.x : 0.f;
            v.y = ok ? v.y : 0.f;
            v.z = ok ? v.z : 0.f;
            v.w = ok ? v.w : 0.f;
            int t = dy * 9 + dx;
            if (NF == 2) {
                float w0 = f0[t];        // uniform -> s_load, no VGPR cost
                float w1 = f1[t];
                a0 = fmaf4(w0, v, a0);
                a1 = fmaf4(w1, v, a1);
            } else {
                float w0 = f0[t];
                float w1 = f0[81 + t];
                float w2 = f0[162 + t];
                float w3 = f0[243 + t];
                a0 = fmaf4(w0, v, a0);
                a1 = fmaf4(w1, v, a1);
                a2 = fmaf4(w2, v, a2);
                a3 = fmaf4(w3, v, a3);
            }
        }
    }
    out0[tid] = a0;
    out1[tid] = a1;
    if (NF == 4) {
        out2[tid] = a2;
        out3[tid] = a3;
    }
}

// 17x17, stride 2, explicit pad 8. logW is log2 of the INPUT width.
__global__ __launch_bounds__(256, 4) void conv17_s2(
    const float4* __restrict__ in, float4* __restrict__ outp,
    const float* __restrict__ f, int logW)
{
    const int W = 1 << logW, Wo = W >> 1;
    int tid = blockIdx.x * 256 + threadIdx.x;
    int c4 = tid & 3;
    int xo = (tid >> 2) & (Wo - 1);
    int yo = (tid >> (1 + logW)) & (Wo - 1);
    int n  = tid >> (2 * logW);
    const float4* base = in + (((size_t)n << (2 * logW)) << 2);

    float4 a = make_float4(0.f, 0.f, 0.f, 0.f);
    #pragma unroll 1
    for (int dy = 0; dy < 17; ++dy) {
        int iy = 2 * yo + dy - 8;
        bool oky = (unsigned)iy < (unsigned)W;
        int iyc = clampi(iy, 0, W - 1);
        #pragma unroll
        for (int dx = 0; dx < 17; ++dx) {
            int ix = 2 * xo + dx - 8;
            bool ok = oky && ((unsigned)ix < (unsigned)W);
            int ixc = clampi(ix, 0, W - 1);
            float4 v = base[(((iyc << logW) + ixc) << 2) + c4];
            float w = f[dy * 17 + dx];   // uniform -> s_load
            w = ok ? w : 0.f;
            a = fmaf4(w, v, a);
        }
    }
    outp[tid] = a;
}

extern "C" void kernel_launch(void* const* d_in, const int* in_sizes, int n_in,
                              void* d_out, int out_size, void* d_ws, size_t ws_size,
                              hipStream_t stream) {
    const float* image   = (const float*)d_in[0];
    const float* lo0filt = (const float*)d_in[1];
    const float* hi0filt = (const float*)d_in[2];
    const float* lofilt  = (const float*)d_in[3];
    const float* bfilts  = (const float*)d_in[4];
    float* out = (float*)d_out;
    float* ws  = (float*)d_ws;

    const int N = 8, C = 16;
    const int logWs[5] = {8, 7, 6, 5, 4};
    size_t sz[5];
    for (int s = 0; s < 5; ++s) sz[s] = (size_t)N * (1 << (2 * logWs[s])) * C;

    // Workspace: lo at scales 0..3 (scale 4 goes straight to d_out).
    float* lo_buf[4];
    size_t woff = 0;
    for (int s = 0; s < 4; ++s) { lo_buf[s] = ws + woff; woff += sz[s]; }

    // Output layout (reversed pyramid, flat-concatenated):
    // [ lo_final | s=3 b=3..0 | s=2 b=3..0 | s=1 b=3..0 | s=0 b=3..0 | hi0 ]
    float* out_lofinal = out;
    size_t o = sz[4];
    float* band_ptr[4][4];
    for (int s = 3; s >= 0; --s)
        for (int b = 3; b >= 0; --b) { band_ptr[s][b] = out + o; o += sz[s]; }
    float* out_hi0 = out + o;

    // hi0 + lo0 from the image (one read, two filters)
    {
        int total = (int)(sz[0] / 4);
        conv9_multi<2><<<total / 256, 256, 0, stream>>>(
            (const float4*)image, (float4*)out_hi0, (float4*)lo_buf[0],
            nullptr, nullptr, hi0filt, lo0filt, logWs[0]);
    }

    for (int s = 0; s < 4; ++s) {
        int total = (int)(sz[s] / 4);
        // 4 band convs fused (one lo read)
        conv9_multi<4><<<total / 256, 256, 0, stream>>>(
            (const float4*)lo_buf[s],
            (float4*)band_ptr[s][0], (float4*)band_ptr[s][1],
            (float4*)band_ptr[s][2], (float4*)band_ptr[s][3],
            bfilts, nullptr, logWs[s]);
        // downsample lo
        int totalo = (int)(sz[s + 1] / 4);
        float4* dst = (s < 3) ? (float4*)lo_buf[s + 1] : (float4*)out_lofinal;
        conv17_s2<<<totalo / 256, 256, 0, stream>>>(
            (const float4*)lo_buf[s], dst, lofilt, logWs[s]);
    }
}

// Round 3
// 334.820 us; speedup vs baseline: 10.8295x; 1.1645x over previous
//
#include <hip/hip_runtime.h>

// Steerable pyramid, depthwise convs, NHWC fp32, C=16 (= 4 x float4).
// Strategy: all conv inputs live in zero-padded workspace buffers so the
// conv kernels are branch-free (no boundary masks, imm-offset loads).

static __device__ __forceinline__ float4 f4z() { return make_float4(0.f, 0.f, 0.f, 0.f); }

static __device__ __forceinline__ float4 fmaf4(float f, float4 v, float4 a) {
    a.x = fmaf(f, v.x, a.x);
    a.y = fmaf(f, v.y, a.y);
    a.z = fmaf(f, v.z, a.z);
    a.w = fmaf(f, v.w, a.w);
    return a;
}

// Copy WxW image into (W+2P)x(W+2P) buffer, zero border. Layout NHWC, float4 units.
template <int W, int P>
__global__ __launch_bounds__(256) void pad_copy(
    const float4* __restrict__ src, float4* __restrict__ dst)
{
    const int Wp = W + 2 * P;
    int tid = blockIdx.x * 256 + threadIdx.x;
    int total = 8 * Wp * Wp * 4;
    if (tid >= total) return;
    int c4 = tid & 3;
    int p  = tid >> 2;
    int n  = p / (Wp * Wp);
    int r  = p - n * (Wp * Wp);
    int yp = r / Wp;
    int xp = r - yp * Wp;
    int y = yp - P, x = xp - P;
    bool ok = ((unsigned)y < (unsigned)W) && ((unsigned)x < (unsigned)W);
    int yc = min(max(y, 0), W - 1), xc = min(max(x, 0), W - 1);
    float4 v = src[(((n * W + yc) * W + xc) << 2) + c4];
    if (!ok) v = f4z();
    dst[tid] = v;
}

// Zero the 8-wide pad border of a (W+16)^2 padded buffer (interior untouched).
template <int W>
__global__ __launch_bounds__(256) void zero_pads(float4* __restrict__ buf)
{
    const int Wp = W + 16;
    const int perN = 16 * Wp + 16 * W;  // top8+bot8 full rows, 8 left + 8 right cols
    int tid = blockIdx.x * 256 + threadIdx.x;
    int total = 8 * perN * 4;
    if (tid >= total) return;
    int c4 = tid & 3;
    int p  = tid >> 2;
    int n  = p / perN;
    int r  = p - n * perN;
    int y, x;
    if (r < 16 * Wp) {
        int row = r / Wp;             // 0..15
        x = r - row * Wp;
        y = (row < 8) ? row : W + row;  // rows 0..7 and W+8..W+15
    } else {
        int q = r - 16 * Wp;          // 0..16W
        y = 8 + (q >> 4);
        int xi = q & 15;
        x = (xi < 8) ? xi : Wp - 16 + xi;
    }
    buf[((size_t)(n * Wp + y) * Wp + x) * 4 + c4] = f4z();
}

// 9x9 conv over padded input (pad INPAD >= 4), branch-free.
// NF==2: f0,f1 separate (hi0->out0 flat, lo0->out1 padded by pad1).
// NF==4: f0 = 4*81 contiguous, all outputs flat.
template <int NF, int LOGW, int INPAD>
__global__ __launch_bounds__(256) void conv9_pad(
    const float4* __restrict__ in,
    float4* __restrict__ out0, float4* __restrict__ out1,
    float4* __restrict__ out2, float4* __restrict__ out3,
    const float* __restrict__ f0, const float* __restrict__ f1,
    int pad1)
{
    const int W  = 1 << LOGW;
    const int Wp = W + 2 * INPAD;
    int tid = blockIdx.x * 256 + threadIdx.x;
    int c4 = tid & 3;
    int x  = (tid >> 2) & (W - 1);
    int y  = (tid >> (2 + LOGW)) & (W - 1);
    int n  = tid >> (2 + 2 * LOGW);

    const float4* row =
        in + ((size_t)(n * Wp + y + INPAD - 4) * Wp + (x + INPAD - 4)) * 4 + c4;

    float4 a0 = f4z(), a1 = f4z(), a2 = f4z(), a3 = f4z();
    #pragma unroll 1
    for (int dy = 0; dy < 9; ++dy) {
        #pragma unroll
        for (int dx = 0; dx < 9; ++dx) {
            float4 v = row[dx * 4];   // imm-offset loads, shared base
            int t = dy * 9 + dx;
            if (NF == 2) {
                a0 = fmaf4(f0[t], v, a0);
                a1 = fmaf4(f1[t], v, a1);
            } else {
                a0 = fmaf4(f0[t], v, a0);
                a1 = fmaf4(f0[81 + t], v, a1);
                a2 = fmaf4(f0[162 + t], v, a2);
                a3 = fmaf4(f0[243 + t], v, a3);
            }
        }
        row += Wp * 4;
    }

    out0[tid] = a0;
    if (NF == 2) {
        int W1 = W + 2 * pad1;
        out1[((size_t)(n * W1 + y + pad1) * W1 + x + pad1) * 4 + c4] = a1;
    } else {
        out1[tid] = a1;
        out2[tid] = a2;
        out3[tid] = a3;
    }
}

// 17x17 stride-2 conv over padded input (pad 8), branch-free. Output Wo=W/2,
// written with outPad (8 -> next lo level, 0 -> final output).
template <int LOGW>
__global__ __launch_bounds__(256) void conv17_s2_pad(
    const float4* __restrict__ in, float4* __restrict__ out,
    const float* __restrict__ f, int outPad)
{
    const int W  = 1 << LOGW;
    const int Wo = W >> 1;
    const int Wp = W + 16;
    int tid = blockIdx.x * 256 + threadIdx.x;
    int c4 = tid & 3;
    int xo = (tid >> 2) & (Wo - 1);
    int yo = (tid >> (1 + LOGW)) & (Wo - 1);
    int n  = tid >> (2 * LOGW);

    const float4* row = in + ((size_t)(n * Wp + 2 * yo) * Wp + 2 * xo) * 4 + c4;

    float4 a = f4z();
    #pragma unroll 1
    for (int dy = 0; dy < 17; ++dy) {
        #pragma unroll
        for (int dx = 0; dx < 17; ++dx)
            a = fmaf4(f[dy * 17 + dx], row[dx * 4], a);
        row += Wp * 4;
    }
    int W1 = Wo + 2 * outPad;
    out[((size_t)(n * W1 + yo + outPad) * W1 + xo + outPad) * 4 + c4] = a;
}

extern "C" void kernel_launch(void* const* d_in, const int* in_sizes, int n_in,
                              void* d_out, int out_size, void* d_ws, size_t ws_size,
                              hipStream_t stream) {
    const float* image   = (const float*)d_in[0];
    const float* lo0filt = (const float*)d_in[1];
    const float* hi0filt = (const float*)d_in[2];
    const float* lofilt  = (const float*)d_in[3];
    const float* bfilts  = (const float*)d_in[4];
    float* out = (float*)d_out;
    float* ws  = (float*)d_ws;

    const int N = 8, C = 16;
    size_t sz[5];
    const int Ws[5] = {256, 128, 64, 32, 16};
    for (int s = 0; s < 5; ++s) sz[s] = (size_t)N * Ws[s] * Ws[s] * C;

    // Workspace ping-pong: A = image pad4 (264^2), later lo1/lo3 (pad8).
    //                      B = lo0 pad8 (272^2), later lo2 (pad8).
    const size_t A_floats = (size_t)N * 264 * 264 * C;   // 8,921,088
    float* A = ws;
    float* B = ws + A_floats;

    // Output layout (reversed pyramid, flat):
    // [ lo_final | s=3 b=3..0 | s=2 b=3..0 | s=1 b=3..0 | s=0 b=3..0 | hi0 ]
    float* out_lofinal = out;
    size_t o = sz[4];
    float* band_ptr[4][4];
    for (int s = 3; s >= 0; --s)
        for (int b = 3; b >= 0; --b) { band_ptr[s][b] = out + o; o += sz[s]; }
    float* out_hi0 = out + o;

    // 1. image -> A (pad 4, zero border)
    pad_copy<256, 4><<<(8 * 264 * 264 * 4) / 256, 256, 0, stream>>>(
        (const float4*)image, (float4*)A);
    // 2. zero pads of lo0 (B)
    zero_pads<256><<<(8 * (16 * 272 + 16 * 256) * 4) / 256, 256, 0, stream>>>((float4*)B);
    // 3. hi0 (flat) + lo0 (B, pad 8) from A
    conv9_pad<2, 8, 4><<<(int)(sz[0] / 4) / 256, 256, 0, stream>>>(
        (const float4*)A, (float4*)out_hi0, (float4*)B, nullptr, nullptr,
        hi0filt, lo0filt, 8);
    // 4. bands s=0 from B
    conv9_pad<4, 8, 8><<<(int)(sz[0] / 4) / 256, 256, 0, stream>>>(
        (const float4*)B, (float4*)band_ptr[0][0], (float4*)band_ptr[0][1],
        (float4*)band_ptr[0][2], (float4*)band_ptr[0][3], bfilts, nullptr, 0);
    // 5. zero pads of lo1 (A reused)
    zero_pads<128><<<(8 * (16 * 144 + 16 * 128) * 4) / 256, 256, 0, stream>>>((float4*)A);
    // 6. lo1 = downsample(lo0): B -> A (pad 8)
    conv17_s2_pad<8><<<(int)(sz[1] / 4) / 256, 256, 0, stream>>>(
        (const float4*)B, (float4*)A, lofilt, 8);
    // 7. bands s=1 from A
    conv9_pad<4, 7, 8><<<(int)(sz[1] / 4) / 256, 256, 0, stream>>>(
        (const float4*)A, (float4*)band_ptr[1][0], (float4*)band_ptr[1][1],
        (float4*)band_ptr[1][2], (float4*)band_ptr[1][3], bfilts, nullptr, 0);
    // 8. zero pads of lo2 (B reused)
    zero_pads<64><<<(8 * (16 * 80 + 16 * 64) * 4) / 256, 256, 0, stream>>>((float4*)B);
    // 9. lo2: A -> B (pad 8)
    conv17_s2_pad<7><<<(int)(sz[2] / 4) / 256, 256, 0, stream>>>(
        (const float4*)A, (float4*)B, lofilt, 8);
    // 10. bands s=2 from B
    conv9_pad<4, 6, 8><<<(int)(sz[2] / 4) / 256, 256, 0, stream>>>(
        (const float4*)B, (float4*)band_ptr[2][0], (float4*)band_ptr[2][1],
        (float4*)band_ptr[2][2], (float4*)band_ptr[2][3], bfilts, nullptr, 0);
    // 11. zero pads of lo3 (A reused)
    zero_pads<32><<<(8 * (16 * 48 + 16 * 32) * 4) / 256, 256, 0, stream>>>((float4*)A);
    // 12. lo3: B -> A (pad 8)
    conv17_s2_pad<6><<<(int)(sz[3] / 4) / 256, 256, 0, stream>>>(
        (const float4*)B, (float4*)A, lofilt, 8);
    // 13. bands s=3 from A
    conv9_pad<4, 5, 8><<<(int)(sz[3] / 4) / 256, 256, 0, stream>>>(
        (const float4*)A, (float4*)band_ptr[3][0], (float4*)band_ptr[3][1],
        (float4*)band_ptr[3][2], (float4*)band_ptr[3][3], bfilts, nullptr, 0);
    // 14. lo_final: A -> d_out (flat)
    conv17_s2_pad<5><<<(int)(sz[4] / 4) / 256, 256, 0, stream>>>(
        (const float4*)A, (float4*)out_lofinal, lofilt, 0);
}

// Round 4
// 280.489 us; speedup vs baseline: 12.9272x; 1.1937x over previous
//
#include <hip/hip_runtime.h>

// Steerable pyramid, depthwise convs, NHWC fp32, C=16 (= 4 x float4).
// All conv inputs live in zero-padded workspace buffers (branch-free convs).
// 4 output pixels per thread (sliding-window column reuse).

static __device__ __forceinline__ float4 f4z() { return make_float4(0.f, 0.f, 0.f, 0.f); }

static __device__ __forceinline__ float4 fmaf4(float f, float4 v, float4 a) {
    a.x = fmaf(f, v.x, a.x);
    a.y = fmaf(f, v.y, a.y);
    a.z = fmaf(f, v.z, a.z);
    a.w = fmaf(f, v.w, a.w);
    return a;
}

// ---------------------------------------------------------------- pad helpers

// Copy 256x256 image into 264x264 buffer (pad 4), zero border.
__global__ __launch_bounds__(256) void pad_copy_img(
    const float4* __restrict__ src, float4* __restrict__ dst)
{
    const int W = 256, P = 4, Wp = 264;
    int tid = blockIdx.x * 256 + threadIdx.x;
    int c4 = tid & 3;
    int p  = tid >> 2;
    int n  = p / (Wp * Wp);
    int r  = p - n * (Wp * Wp);
    int yp = r / Wp;
    int xp = r - yp * Wp;
    int y = yp - P, x = xp - P;
    bool ok = ((unsigned)y < (unsigned)W) && ((unsigned)x < (unsigned)W);
    int yc = min(max(y, 0), W - 1), xc = min(max(x, 0), W - 1);
    float4 v = src[(((n * W + yc) * W + xc) << 2) + c4];
    if (!ok) v = f4z();
    dst[tid] = v;
}

// Zero the 8-wide pad borders of all four lo buffers in ONE launch.
// Block ranges: L0(W=256):1056, L1(128):544, L2(64):288, L3(32):160 -> 2048 total.
__global__ __launch_bounds__(256) void zero_pads_all(
    float4* __restrict__ L0, float4* __restrict__ L1,
    float4* __restrict__ L2, float4* __restrict__ L3)
{
    int b = blockIdx.x;
    float4* buf; int W;
    if (b < 1056)      { buf = L0; W = 256; }
    else if (b < 1600) { buf = L1; W = 128; b -= 1056; }
    else if (b < 1888) { buf = L2; W = 64;  b -= 1600; }
    else               { buf = L3; W = 32;  b -= 1888; }
    int Wp = W + 16;
    int perN = 16 * Wp + 16 * W;
    int tid = b * 256 + threadIdx.x;
    int c4 = tid & 3;
    int p  = tid >> 2;
    int n  = p / perN;
    int r  = p - n * perN;
    int y, x;
    if (r < 16 * Wp) {
        int row = r / Wp;
        x = r - row * Wp;
        y = (row < 8) ? row : (W + row);
    } else {
        int q = r - 16 * Wp;
        y = 8 + (q >> 4);
        int xi = q & 15;
        x = (xi < 8) ? xi : (Wp - 16 + xi);
    }
    buf[((size_t)(n * Wp + y) * Wp + x) * 4 + c4] = f4z();
}

// ---------------------------------------------------------------- convs

// hi0 + lo0 from padded image (pad 4). 4 pixels/thread.
__global__ __launch_bounds__(256) void conv9_dual4(
    const float4* __restrict__ in,   // 264 wide, pad 4
    float4* __restrict__ hi0,        // flat 256
    float4* __restrict__ lo0,        // 272 wide, pad 8
    const float* __restrict__ fh, const float* __restrict__ fl)
{
    const int W = 256, Wp = 264;
    int tid = blockIdx.x * 256 + threadIdx.x;
    int c4 = tid & 3;
    int xg = (tid >> 2) & 63;
    int y  = (tid >> 8) & 255;
    int n  = tid >> 16;
    int x0 = xg * 4;
    const float4* row = in + ((size_t)(n * Wp + y) * Wp + x0) * 4 + c4;

    float4 ah[4], al[4];
    #pragma unroll
    for (int p = 0; p < 4; ++p) { ah[p] = f4z(); al[p] = f4z(); }

    #pragma unroll 1
    for (int dy = 0; dy < 9; ++dy) {
        float4 v[12];
        #pragma unroll
        for (int j = 0; j < 12; ++j) v[j] = row[j * 4];
        #pragma unroll
        for (int dx = 0; dx < 9; ++dx) {
            int t = dy * 9 + dx;
            float wh = fh[t], wl = fl[t];
            #pragma unroll
            for (int p = 0; p < 4; ++p) {
                ah[p] = fmaf4(wh, v[p + dx], ah[p]);
                al[p] = fmaf4(wl, v[p + dx], al[p]);
            }
        }
        row += Wp * 4;
    }
    #pragma unroll
    for (int p = 0; p < 4; ++p) {
        hi0[((size_t)(n * W + y) * W + x0 + p) * 4 + c4] = ah[p];
        lo0[((size_t)(n * 272 + y + 8) * 272 + x0 + p + 8) * 4 + c4] = al[p];
    }
}

// Fused per-scale kernel: blocks [0, bandsBlocks) compute the 4 band convs
// (9x9), blocks [bandsBlocks, ...) compute the 17x17 stride-2 downsample.
// Input is the padded (pad 8) lo buffer, width Wp = W + 16. 4 pixels/thread.
template <int LOGW>
__global__ __launch_bounds__(256) void scale_fused(
    const float4* __restrict__ in,
    float4* __restrict__ b0, float4* __restrict__ b1,
    float4* __restrict__ b2, float4* __restrict__ b3,
    float4* __restrict__ lo_out,
    const float* __restrict__ bf,    // 4*81 contiguous
    const float* __restrict__ lf,    // 17*17
    int bandsBlocks, int outPad)
{
    const int W = 1 << LOGW, Wp = W + 16;
    if ((int)blockIdx.x < bandsBlocks) {
        int tid = blockIdx.x * 256 + threadIdx.x;
        int c4 = tid & 3;
        int xg = (tid >> 2) & (W / 4 - 1);
        int y  = (tid >> LOGW) & (W - 1);
        int n  = tid >> (2 * LOGW);
        int x0 = xg * 4;
        const float4* row = in + ((size_t)(n * Wp + y + 4) * Wp + (x0 + 4)) * 4 + c4;

        float4 acc[4][4];
        #pragma unroll
        for (int p = 0; p < 4; ++p)
            #pragma unroll
            for (int f = 0; f < 4; ++f) acc[p][f] = f4z();

        #pragma unroll 1
        for (int dy = 0; dy < 9; ++dy) {
            float4 v[12];
            #pragma unroll
            for (int j = 0; j < 12; ++j) v[j] = row[j * 4];
            #pragma unroll
            for (int dx = 0; dx < 9; ++dx) {
                int t = dy * 9 + dx;
                float w0 = bf[t], w1 = bf[81 + t], w2 = bf[162 + t], w3 = bf[243 + t];
                #pragma unroll
                for (int p = 0; p < 4; ++p) {
                    acc[p][0] = fmaf4(w0, v[p + dx], acc[p][0]);
                    acc[p][1] = fmaf4(w1, v[p + dx], acc[p][1]);
                    acc[p][2] = fmaf4(w2, v[p + dx], acc[p][2]);
                    acc[p][3] = fmaf4(w3, v[p + dx], acc[p][3]);
                }
            }
            row += Wp * 4;
        }
        #pragma unroll
        for (int p = 0; p < 4; ++p) {
            size_t idx = ((size_t)(n * W + y) * W + x0 + p) * 4 + c4;
            b0[idx] = acc[p][0];
            b1[idx] = acc[p][1];
            b2[idx] = acc[p][2];
            b3[idx] = acc[p][3];
        }
    } else {
        const int Wo = W >> 1;
        int tid = ((int)blockIdx.x - bandsBlocks) * 256 + threadIdx.x;
        int c4 = tid & 3;
        int xg = (tid >> 2) & (Wo / 4 - 1);
        int yo = (tid >> (LOGW - 1)) & (Wo - 1);
        int n  = tid >> (2 * LOGW - 2);
        int xo0 = xg * 4;
        const float4* row = in + ((size_t)(n * Wp + 2 * yo) * Wp + 2 * xo0) * 4 + c4;

        float4 acc[4];
        #pragma unroll
        for (int p = 0; p < 4; ++p) acc[p] = f4z();

        #pragma unroll 1
        for (int dy = 0; dy < 17; ++dy) {
            float4 v[23];
            #pragma unroll
            for (int j = 0; j < 23; ++j) v[j] = row[j * 4];
            #pragma unroll
            for (int dx = 0; dx < 17; ++dx) {
                float w = lf[dy * 17 + dx];
                #pragma unroll
                for (int p = 0; p < 4; ++p)
                    acc[p] = fmaf4(w, v[2 * p + dx], acc[p]);
            }
            row += Wp * 4;
        }
        int W1 = Wo + 2 * outPad;
        #pragma unroll
        for (int p = 0; p < 4; ++p)
            lo_out[((size_t)(n * W1 + yo + outPad) * W1 + xo0 + p + outPad) * 4 + c4] = acc[p];
    }
}

// ---------------------------------------------------------------- launch

extern "C" void kernel_launch(void* const* d_in, const int* in_sizes, int n_in,
                              void* d_out, int out_size, void* d_ws, size_t ws_size,
                              hipStream_t stream) {
    const float* image   = (const float*)d_in[0];
    const float* lo0filt = (const float*)d_in[1];
    const float* hi0filt = (const float*)d_in[2];
    const float* lofilt  = (const float*)d_in[3];
    const float* bfilts  = (const float*)d_in[4];
    float* out = (float*)d_out;
    float* ws  = (float*)d_ws;

    const int N = 8, C = 16;
    size_t sz[5];
    const int Ws[5] = {256, 128, 64, 32, 16};
    for (int s = 0; s < 5; ++s) sz[s] = (size_t)N * Ws[s] * Ws[s] * C;

    // Workspace: P0 = image pad4 (264^2); L0..L3 = lo0..lo3 pad8.
    float* P0 = ws;
    float* L0 = P0 + (size_t)N * 264 * 264 * C;
    float* L1 = L0 + (size_t)N * 272 * 272 * C;
    float* L2 = L1 + (size_t)N * 144 * 144 * C;
    float* L3 = L2 + (size_t)N * 80 * 80 * C;

    // Output layout (reversed pyramid, flat):
    // [ lo_final | s=3 b=3..0 | s=2 b=3..0 | s=1 b=3..0 | s=0 b=3..0 | hi0 ]
    float* out_lofinal = out;
    size_t o = sz[4];
    float* band_ptr[4][4];
    for (int s = 3; s >= 0; --s)
        for (int b = 3; b >= 0; --b) { band_ptr[s][b] = out + o; o += sz[s]; }
    float* out_hi0 = out + o;

    // 1. zero pad borders of L0..L3 (single launch)
    zero_pads_all<<<2048, 256, 0, stream>>>(
        (float4*)L0, (float4*)L1, (float4*)L2, (float4*)L3);
    // 2. image -> P0 (pad 4)
    pad_copy_img<<<(8 * 264 * 264 * 4) / 256, 256, 0, stream>>>(
        (const float4*)image, (float4*)P0);
    // 3. hi0 (flat) + lo0 (L0) from P0
    conv9_dual4<<<2048, 256, 0, stream>>>(
        (const float4*)P0, (float4*)out_hi0, (float4*)L0, hi0filt, lo0filt);
    // 4..7. per-scale fused: bands_s + lo_{s+1}
    {
        int bb = 256 * 256 / 32, db = 256 * 256 / 128;
        scale_fused<8><<<bb + db, 256, 0, stream>>>(
            (const float4*)L0, (float4*)band_ptr[0][0], (float4*)band_ptr[0][1],
            (float4*)band_ptr[0][2], (float4*)band_ptr[0][3], (float4*)L1,
            bfilts, lofilt, bb, 8);
    }
    {
        int bb = 128 * 128 / 32, db = 128 * 128 / 128;
        scale_fused<7><<<bb + db, 256, 0, stream>>>(
            (const float4*)L1, (float4*)band_ptr[1][0], (float4*)band_ptr[1][1],
            (float4*)band_ptr[1][2], (float4*)band_ptr[1][3], (float4*)L2,
            bfilts, lofilt, bb, 8);
    }
    {
        int bb = 64 * 64 / 32, db = 64 * 64 / 128;
        scale_fused<6><<<bb + db, 256, 0, stream>>>(
            (const float4*)L2, (float4*)band_ptr[2][0], (float4*)band_ptr[2][1],
            (float4*)band_ptr[2][2], (float4*)band_ptr[2][3], (float4*)L3,
            bfilts, lofilt, bb, 8);
    }
    {
        int bb = 32 * 32 / 32, db = 32 * 32 / 128;
        scale_fused<5><<<bb + db, 256, 0, stream>>>(
            (const float4*)L3, (float4*)band_ptr[3][0], (float4*)band_ptr[3][1],
            (float4*)band_ptr[3][2], (float4*)band_ptr[3][3], (float4*)out_lofinal,
            bfilts, lofilt, bb, 0);
    }
}

// Round 5
// 233.727 us; speedup vs baseline: 15.5136x; 1.2001x over previous
//
#include <hip/hip_runtime.h>

// Steerable pyramid, depthwise convs, NHWC fp32, C=16 (= 4 x float4).
// Branch-free convs over zero-padded workspace buffers.
// 4 output pixels per thread (sliding-window column reuse).
// XCD-aware scheduling: n = blockIdx & 7 (8 images -> 8 XCDs), y swept in
// order per XCD so the dy-loop row window stays resident in that XCD's L2.

static __device__ __forceinline__ float4 f4z() { return make_float4(0.f, 0.f, 0.f, 0.f); }

static __device__ __forceinline__ float4 fmaf4(float f, float4 v, float4 a) {
    a.x = fmaf(f, v.x, a.x);
    a.y = fmaf(f, v.y, a.y);
    a.z = fmaf(f, v.z, a.z);
    a.w = fmaf(f, v.w, a.w);
    return a;
}

// ---------------------------------------------------------------- pad helpers

// Copy 256x256 image into 264x264 buffer (pad 4), zero border. n = b&7.
__global__ __launch_bounds__(256) void pad_copy_img(
    const float4* __restrict__ src, float4* __restrict__ dst)
{
    const int W = 256, P = 4, Wp = 264;
    int n = blockIdx.x & 7;
    int q = blockIdx.x >> 3;                 // 1089 per n
    int e = q * 256 + threadIdx.x;           // < 264*264*4 exactly
    int c4 = e & 3;
    int pix = e >> 2;                        // < 264*264
    int yp = pix / Wp;
    int xp = pix - yp * Wp;
    int y = yp - P, x = xp - P;
    bool ok = ((unsigned)y < (unsigned)W) && ((unsigned)x < (unsigned)W);
    int yc = min(max(y, 0), W - 1), xc = min(max(x, 0), W - 1);
    float4 v = src[(((n * W + yc) * W + xc) << 2) + c4];
    if (!ok) v = f4z();
    dst[((size_t)n * Wp * Wp + pix) * 4 + c4] = v;
}

// Zero the 8-wide pad borders of all four lo buffers in ONE launch.
// Block ranges: L0(W=256):1056, L1(128):544, L2(64):288, L3(32):160 -> 2048 total.
__global__ __launch_bounds__(256) void zero_pads_all(
    float4* __restrict__ L0, float4* __restrict__ L1,
    float4* __restrict__ L2, float4* __restrict__ L3)
{
    int b = blockIdx.x;
    float4* buf; int W;
    if (b < 1056)      { buf = L0; W = 256; }
    else if (b < 1600) { buf = L1; W = 128; b -= 1056; }
    else if (b < 1888) { buf = L2; W = 64;  b -= 1600; }
    else               { buf = L3; W = 32;  b -= 1888; }
    int Wp = W + 16;
    int perN = 16 * Wp + 16 * W;
    int tid = b * 256 + threadIdx.x;
    int c4 = tid & 3;
    int p  = tid >> 2;
    int n  = p / perN;
    int r  = p - n * perN;
    int y, x;
    if (r < 16 * Wp) {
        int row = r / Wp;
        x = r - row * Wp;
        y = (row < 8) ? row : (W + row);
    } else {
        int q = r - 16 * Wp;
        y = 8 + (q >> 4);
        int xi = q & 15;
        x = (xi < 8) ? xi : (Wp - 16 + xi);
    }
    buf[((size_t)(n * Wp + y) * Wp + x) * 4 + c4] = f4z();
}

// ---------------------------------------------------------------- convs

// hi0 + lo0 from padded image (pad 4). 4 px/thread. One y row per block.
// n = b&7, y = b>>3.
__global__ __launch_bounds__(256) void conv9_dual4(
    const float4* __restrict__ in,   // 264 wide, pad 4
    float4* __restrict__ hi0,        // flat 256
    float4* __restrict__ lo0,        // 272 wide, pad 8
    const float* __restrict__ fh, const float* __restrict__ fl)
{
    const int W = 256, Wp = 264;
    int n = blockIdx.x & 7;
    int y = blockIdx.x >> 3;
    int t = threadIdx.x;
    int c4 = t & 3;
    int xg = t >> 2;                 // 0..63
    int x0 = xg * 4;
    const float4* row = in + ((size_t)(n * Wp + y) * Wp + x0) * 4 + c4;

    float4 ah[4], al[4];
    #pragma unroll
    for (int p = 0; p < 4; ++p) { ah[p] = f4z(); al[p] = f4z(); }

    #pragma unroll 1
    for (int dy = 0; dy < 9; ++dy) {
        float4 v[12];
        #pragma unroll
        for (int j = 0; j < 12; ++j) v[j] = row[j * 4];
        #pragma unroll
        for (int dx = 0; dx < 9; ++dx) {
            int tt = dy * 9 + dx;
            float wh = fh[tt], wl = fl[tt];
            #pragma unroll
            for (int p = 0; p < 4; ++p) {
                ah[p] = fmaf4(wh, v[p + dx], ah[p]);
                al[p] = fmaf4(wl, v[p + dx], al[p]);
            }
        }
        row += Wp * 4;
    }
    #pragma unroll
    for (int p = 0; p < 4; ++p) {
        hi0[((size_t)(n * W + y) * W + x0 + p) * 4 + c4] = ah[p];
        lo0[((size_t)(n * 272 + y + 8) * 272 + x0 + p + 8) * 4 + c4] = al[p];
    }
}

// Fused per-scale kernel. n = b&7; q = b>>3. q < bandsPerN -> 9x9 quad bands,
// else 17x17 stride-2 downsample. Input: padded (pad 8) lo, Wp = W+16.
// 4 px/thread; y swept in order per XCD.
template <int LOGW>
__global__ __launch_bounds__(256) void scale_fused(
    const float4* __restrict__ in,
    float4* __restrict__ b0, float4* __restrict__ b1,
    float4* __restrict__ b2, float4* __restrict__ b3,
    float4* __restrict__ lo_out,
    const float* __restrict__ bf,    // 4*81 contiguous
    const float* __restrict__ lf,    // 17*17
    int outPad)
{
    const int W = 1 << LOGW, Wp = W + 16;
    const int bandsPerN = (W * W) >> 8;      // blocks per image for bands
    int n = blockIdx.x & 7;
    int q = blockIdx.x >> 3;
    int t = threadIdx.x;
    int c4 = t & 3;

    if (q < bandsPerN) {
        int xg = (t >> 2) & (W / 4 - 1);
        int ry = t >> LOGW;                  // rows-per-block = 256/W
        int y  = q * (256 >> LOGW) + ry;
        int x0 = xg * 4;
        const float4* row = in + ((size_t)(n * Wp + y + 4) * Wp + (x0 + 4)) * 4 + c4;

        float4 acc[4][4];
        #pragma unroll
        for (int p = 0; p < 4; ++p)
            #pragma unroll
            for (int f = 0; f < 4; ++f) acc[p][f] = f4z();

        #pragma unroll 1
        for (int dy = 0; dy < 9; ++dy) {
            float4 v[12];
            #pragma unroll
            for (int j = 0; j < 12; ++j) v[j] = row[j * 4];
            #pragma unroll
            for (int dx = 0; dx < 9; ++dx) {
                int tt = dy * 9 + dx;
                float w0 = bf[tt], w1 = bf[81 + tt], w2 = bf[162 + tt], w3 = bf[243 + tt];
                #pragma unroll
                for (int p = 0; p < 4; ++p) {
                    acc[p][0] = fmaf4(w0, v[p + dx], acc[p][0]);
                    acc[p][1] = fmaf4(w1, v[p + dx], acc[p][1]);
                    acc[p][2] = fmaf4(w2, v[p + dx], acc[p][2]);
                    acc[p][3] = fmaf4(w3, v[p + dx], acc[p][3]);
                }
            }
            row += Wp * 4;
        }
        #pragma unroll
        for (int p = 0; p < 4; ++p) {
            size_t idx = ((size_t)(n * W + y) * W + x0 + p) * 4 + c4;
            b0[idx] = acc[p][0];
            b1[idx] = acc[p][1];
            b2[idx] = acc[p][2];
            b3[idx] = acc[p][3];
        }
    } else {
        const int Wo = W >> 1;
        int q2 = q - bandsPerN;
        int xg = (t >> 2) & (Wo / 4 - 1);
        int ry = t >> (LOGW - 1);            // rows-per-block = 256/Wo
        int yo = q2 * (256 >> (LOGW - 1)) + ry;
        int xo0 = xg * 4;
        const float4* row = in + ((size_t)(n * Wp + 2 * yo) * Wp + 2 * xo0) * 4 + c4;

        float4 acc[4];
        #pragma unroll
        for (int p = 0; p < 4; ++p) acc[p] = f4z();

        #pragma unroll 1
        for (int dy = 0; dy < 17; ++dy) {
            float4 v[23];
            #pragma unroll
            for (int j = 0; j < 23; ++j) v[j] = row[j * 4];
            #pragma unroll
            for (int dx = 0; dx < 17; ++dx) {
                float w = lf[dy * 17 + dx];
                #pragma unroll
                for (int p = 0; p < 4; ++p)
                    acc[p] = fmaf4(w, v[2 * p + dx], acc[p]);
            }
            row += Wp * 4;
        }
        int W1 = Wo + 2 * outPad;
        #pragma unroll
        for (int p = 0; p < 4; ++p)
            lo_out[((size_t)(n * W1 + yo + outPad) * W1 + xo0 + p + outPad) * 4 + c4] = acc[p];
    }
}

// ---------------------------------------------------------------- launch

extern "C" void kernel_launch(void* const* d_in, const int* in_sizes, int n_in,
                              void* d_out, int out_size, void* d_ws, size_t ws_size,
                              hipStream_t stream) {
    const float* image   = (const float*)d_in[0];
    const float* lo0filt = (const float*)d_in[1];
    const float* hi0filt = (const float*)d_in[2];
    const float* lofilt  = (const float*)d_in[3];
    const float* bfilts  = (const float*)d_in[4];
    float* out = (float*)d_out;
    float* ws  = (float*)d_ws;

    const int N = 8, C = 16;
    size_t sz[5];
    const int Ws[5] = {256, 128, 64, 32, 16};
    for (int s = 0; s < 5; ++s) sz[s] = (size_t)N * Ws[s] * Ws[s] * C;

    // Workspace: P0 = image pad4 (264^2); L0..L3 = lo0..lo3 pad8.
    float* P0 = ws;
    float* L0 = P0 + (size_t)N * 264 * 264 * C;
    float* L1 = L0 + (size_t)N * 272 * 272 * C;
    float* L2 = L1 + (size_t)N * 144 * 144 * C;
    float* L3 = L2 + (size_t)N * 80 * 80 * C;

    // Output layout (reversed pyramid, flat):
    // [ lo_final | s=3 b=3..0 | s=2 b=3..0 | s=1 b=3..0 | s=0 b=3..0 | hi0 ]
    float* out_lofinal = out;
    size_t o = sz[4];
    float* band_ptr[4][4];
    for (int s = 3; s >= 0; --s)
        for (int b = 3; b >= 0; --b) { band_ptr[s][b] = out + o; o += sz[s]; }
    float* out_hi0 = out + o;

    // 1. zero pad borders of L0..L3 (single launch)
    zero_pads_all<<<2048, 256, 0, stream>>>(
        (float4*)L0, (float4*)L1, (float4*)L2, (float4*)L3);
    // 2. image -> P0 (pad 4); 1089 blocks per image, n = b&7
    pad_copy_img<<<8 * 1089, 256, 0, stream>>>(
        (const float4*)image, (float4*)P0);
    // 3. hi0 (flat) + lo0 (L0) from P0; one y row per block, n = b&7
    conv9_dual4<<<2048, 256, 0, stream>>>(
        (const float4*)P0, (float4*)out_hi0, (float4*)L0, hi0filt, lo0filt);
    // 4..7. per-scale fused: bands_s + lo_{s+1}; grid = 8*(bandsPerN + downPerN)
    scale_fused<8><<<8 * (256 + 64), 256, 0, stream>>>(
        (const float4*)L0, (float4*)band_ptr[0][0], (float4*)band_ptr[0][1],
        (float4*)band_ptr[0][2], (float4*)band_ptr[0][3], (float4*)L1,
        bfilts, lofilt, 8);
    scale_fused<7><<<8 * (64 + 16), 256, 0, stream>>>(
        (const float4*)L1, (float4*)band_ptr[1][0], (float4*)band_ptr[1][1],
        (float4*)band_ptr[1][2], (float4*)band_ptr[1][3], (float4*)L2,
        bfilts, lofilt, 8);
    scale_fused<6><<<8 * (16 + 4), 256, 0, stream>>>(
        (const float4*)L2, (float4*)band_ptr[2][0], (float4*)band_ptr[2][1],
        (float4*)band_ptr[2][2], (float4*)band_ptr[2][3], (float4*)L3,
        bfilts, lofilt, 8);
    scale_fused<5><<<8 * (4 + 1), 256, 0, stream>>>(
        (const float4*)L3, (float4*)band_ptr[3][0], (float4*)band_ptr[3][1],
        (float4*)band_ptr[3][2], (float4*)band_ptr[3][3], (float4*)out_lofinal,
        bfilts, lofilt, 0);
}